// Round 4
// baseline (580.521 us; speedup 1.0000x reference)
//
#include <hip/hip_runtime.h>
#include <stdint.h>

typedef unsigned short u16;
typedef unsigned int u32;
typedef __attribute__((ext_vector_type(8))) short short8v;   // 8 bf16 = 4 VGPRs
typedef __attribute__((ext_vector_type(4))) float f32x4;

#define NB 16      // batches per block -> 512 blocks -> 2 blocks/CU
#define HISTN 64
#define TGEN 193   // L+1

// strides (elements)
#define S_NOISE 2048   // 256*8
#define S_HIST  192    // 64*3
#define S_GAP   386    // 193*2
#define S_OUT   771    // 257*3

// h buffer row stride: 104 u16 = 208 B = 52 dwords (52%32=20 -> ln,ln+8 pairs
// land same-bank/diff-addr = 2-way = free for b128 reads). Only k0..63 used.
#define HROW 104

__device__ __forceinline__ float b2f(u16 u) { return __uint_as_float(((u32)u) << 16); }
__device__ __forceinline__ u16 f2b(float f) {
    u32 u = __float_as_uint(f);
    u32 r = (u + 0x7fffu + ((u >> 16) & 1u)) >> 16;
    return (u16)r;
}
// fast transcendentals: v_rcp_f32 (~1 ulp) instead of full-precision v_div
__device__ __forceinline__ float rcp_(float x) { return __builtin_amdgcn_rcpf(x); }
__device__ __forceinline__ float sigf(float x) { return rcp_(1.0f + __expf(-x)); }
__device__ __forceinline__ float tanhf_(float x) {
    return __builtin_fmaf(-2.0f, rcp_(1.0f + __expf(2.0f * x)), 1.0f);
}
__device__ __forceinline__ float ldv(const void* p, int idx, bool f32) {
    return f32 ? ((const float*)p)[idx] : b2f(((const u16*)p)[idx]);
}
// LDS-only barrier: drain LDS ops; global prefetch rides across (no vmcnt drain)
__device__ __forceinline__ void sync_lds() {
    asm volatile("s_waitcnt lgkmcnt(0)" ::: "memory");
    __builtin_amdgcn_s_barrier();
}

extern "C" __global__ void __launch_bounds__(512, 4)
lstm_gen_kernel(const void* __restrict__ noise, const void* __restrict__ hist_x,
                const void* __restrict__ gap, const void* __restrict__ pW_ih,
                const void* __restrict__ pW_hh, const void* __restrict__ pb_ih,
                const void* __restrict__ pb_hh, const void* __restrict__ pW1,
                const void* __restrict__ pb1, const void* __restrict__ pW2,
                const void* __restrict__ pb2, void* __restrict__ out)
{
    __shared__ u16 hst[2][NB * HROW];        // double-buffered h, 6656 B
    __shared__ float hxl[HISTN][NB][3];      // fp32-staged hist, 12288 B
    __shared__ float zpl[NB * 4];            // MLP per-wave partials, 256 B

    const int tid = threadIdx.x;
    const int lane = tid & 63;
    const int w = tid >> 6;        // wave 0..7
    const int lg = lane >> 4;      // k-group / C-row group
    const int ln = lane & 15;      // A-row / batch column

    // ---- dtype detection (proven logic) ----
    bool is_f32 = false;
    {
        const u32* p = (const u32*)pW_hh;
        for (int i = 0; i < 64; i++) {
            u32 v = p[i];
            float a = b2f((u16)(v & 0xffffu));
            float bb = b2f((u16)(v >> 16));
            if (!(fabsf(a) <= 0.5f) || !(fabsf(bb) <= 0.5f)) is_f32 = true;
        }
    }

    // zero both h buffers (2*NB*HROW u16 = NB*HROW u32)
    for (int i = tid; i < NB * HROW; i += 512) ((u32*)hst)[i] = 0u;
    // stage hist as fp32 (exact pass-through either dtype)
    for (int i = tid; i < HISTN * NB * 3; i += 512) {
        int t = i / 48, r = i % 48, b = r / 3, k = r % 3;
        hxl[t][b][k] = ldv(hist_x, ((size_t)blockIdx.x * NB + b) * S_HIST + t * 3 + k, is_f32);
    }

    // ---- persistent A fragments: wave w owns gate-row tiles [16w,+16) and [128+16w,+16)
    // rows r' = j*4+g (unit-major). A lane: row=ln -> j=T*32+4w+(ln>>2), g=ln&3 ----
    short8v a00, a01, a02, a10, a11, a12;
#pragma unroll
    for (int T = 0; T < 2; T++) {
        const int j = (T << 5) | (w << 2) | (ln >> 2);
        const int g = ln & 3;
        const int row = (g << 6) | j;   // original weight row = gate*64 + unit
        short8v f0, f1, f2;
#pragma unroll
        for (int e = 0; e < 8; e++) {
            const int c = lg * 8 + e;
            f0[e] = (short)f2b(ldv(pW_hh, row * 64 + c, is_f32));
            f1[e] = (short)f2b(ldv(pW_hh, row * 64 + 32 + c, is_f32));
            // x-block k-map: k0,k1 = gd cols 0,1 ; k8..15 = noise cols 4..11 ;
            // dp/dist (cols 2,3) go through the exact fp32 FMA path instead.
            u16 v = 0;
            if (c == 0 || c == 1) v = f2b(ldv(pW_ih, row * 12 + c, is_f32));
            else if (c >= 8 && c < 16) v = f2b(ldv(pW_ih, row * 12 + (c - 4), is_f32));
            f2[e] = (short)v;
        }
        if (T == 0) { a00 = f0; a01 = f1; a02 = f2; }
        else        { a10 = f0; a11 = f1; a12 = f2; }
    }

    // C-side: rows r' = T*128 + 16w + lg*4 + q -> bias + dp/dist weight columns
    f32x4 bias0, bias1, wd0, wd1, ws0, ws1;
#pragma unroll
    for (int T = 0; T < 2; T++) {
        const int jc = (T << 5) | (w << 2) | lg;
        f32x4 bv, dv, sv;
#pragma unroll
        for (int q = 0; q < 4; q++) {
            const int row = (q << 6) | jc;
            bv[q] = ldv(pb_ih, row, is_f32) + ldv(pb_hh, row, is_f32);
            dv[q] = ldv(pW_ih, row * 12 + 2, is_f32);
            sv[q] = ldv(pW_ih, row * 12 + 3, is_f32);
        }
        if (T == 0) { bias0 = bv; wd0 = dv; ws0 = sv; }
        else        { bias1 = bv; wd1 = dv; ws1 = sv; }
    }

    // ---- MLP head fragments (waves 4..7 own W1 rows 16(w-4)..+16) ----
    const bool mlpw = (w >= 4);
    short8v w1F0 = {}, w1F1 = {};
    f32x4 b1v = {0.f, 0.f, 0.f, 0.f};
    float w2L[4] = {0.f, 0.f, 0.f, 0.f};
    if (mlpw) {
        const int wp = w - 4;
        const int row1 = (wp << 4) | ln;
#pragma unroll
        for (int e = 0; e < 8; e++) {
            w1F0[e] = (short)f2b(ldv(pW1, row1 * 64 + lg * 8 + e, is_f32));
            w1F1[e] = (short)f2b(ldv(pW1, row1 * 64 + 32 + lg * 8 + e, is_f32));
        }
        const int rq = (wp << 4) | (lg << 2);
#pragma unroll
        for (int q = 0; q < 4; q++) {
            b1v[q] = ldv(pb1, rq + q, is_f32);
            w2L[q] = ldv(pW2, rq + q, is_f32);
        }
    }

    const float b2v = ldv(pb2, 0, is_f32);

    // ---- per-lane batch pointers (batch = ln for every lane) ----
    const size_t gb = (size_t)blockIdx.x * NB + (size_t)ln;
    const u16* nz_h = (const u16*)noise + gb * S_NOISE;
    const float* nz_f = (const float*)noise + gb * S_NOISE;
    const u16* gd_h = (const u16*)gap + gb * S_GAP;
    const float* gd_f = (const float*)gap + gb * S_GAP;
    u16* out_h = (u16*)out + gb * S_OUT;
    float* out_f = (float*)out + gb * S_OUT;
    const bool writer = (tid < NB);   // wave 0, lg 0, lane ln

    float dist = 0.0f;
    float cv0 = 0.f, cv1 = 0.f;          // gd prefetch (lg0 lanes)
    u32 n01 = 0, n23 = 0, n45 = 0, n67 = 0;  // noise prefetch (lg1 lanes)

    auto ldnoise = [&](int t) {
        if (is_f32) {
            const float4* q = (const float4*)(nz_f + t * 8);
            float4 a = q[0], bq = q[1];
            n01 = (u32)f2b(a.x) | ((u32)f2b(a.y) << 16);
            n23 = (u32)f2b(a.z) | ((u32)f2b(a.w) << 16);
            n45 = (u32)f2b(bq.x) | ((u32)f2b(bq.y) << 16);
            n67 = (u32)f2b(bq.z) | ((u32)f2b(bq.w) << 16);
        } else {
            uint4 nv = *(const uint4*)(nz_h + t * 8);
            n01 = nv.x; n23 = nv.y; n45 = nv.z; n67 = nv.w;
        }
    };
    auto ldgd = [&](int tg) {
        if (is_f32) { cv0 = gd_f[tg * 2]; cv1 = gd_f[tg * 2 + 1]; }
        else { u32 g = *(const u32*)(gd_h + tg * 2);
               cv0 = b2f((u16)(g & 0xffffu)); cv1 = b2f((u16)(g >> 16)); }
    };
    auto mkbf2 = [&](float xa, float xb) {
        short8v z = {};
        if (lg == 0) { z[0] = (short)f2b(xa); z[1] = (short)f2b(xb); }
        else if (lg == 1) {
            z[0] = (short)(n01 & 0xffffu); z[1] = (short)(n01 >> 16);
            z[2] = (short)(n23 & 0xffffu); z[3] = (short)(n23 >> 16);
            z[4] = (short)(n45 & 0xffffu); z[5] = (short)(n45 >> 16);
            z[6] = (short)(n67 & 0xffffu); z[7] = (short)(n67 >> 16);
        }
        return z;
    };

    if (lg == 1) ldnoise(0);
    float cst0 = 0.f, cst1 = 0.f;
    int pc = 0;
    __syncthreads();

    // ================= conditioning: 64 steps, ONE barrier each =================
#pragma unroll 1
    for (int t = 0; t < HISTN; t++) {
        const u16* hc = hst[pc];
        u16* hn = hst[pc ^ 1];
        short8v bf0 = *(const short8v*)&hc[ln * HROW + lg * 8];
        short8v bf1 = *(const short8v*)&hc[ln * HROW + 32 + lg * 8];
        float x2 = hxl[t][ln][2];
        float x0f = 0.f, x1f = 0.f;
        if (lg == 0) { x0f = hxl[t][ln][0]; x1f = hxl[t][ln][1]; }
        dist += x2;
        short8v bf2 = mkbf2(x0f, x1f);
        f32x4 acc0 = bias0, acc1 = bias1;
        acc0 = __builtin_amdgcn_mfma_f32_16x16x32_bf16(a00, bf0, acc0, 0, 0, 0);
        acc0 = __builtin_amdgcn_mfma_f32_16x16x32_bf16(a01, bf1, acc0, 0, 0, 0);
        acc0 = __builtin_amdgcn_mfma_f32_16x16x32_bf16(a02, bf2, acc0, 0, 0, 0);
        acc1 = __builtin_amdgcn_mfma_f32_16x16x32_bf16(a10, bf0, acc1, 0, 0, 0);
        acc1 = __builtin_amdgcn_mfma_f32_16x16x32_bf16(a11, bf1, acc1, 0, 0, 0);
        acc1 = __builtin_amdgcn_mfma_f32_16x16x32_bf16(a12, bf2, acc1, 0, 0, 0);
#pragma unroll
        for (int q = 0; q < 4; q++) {
            acc0[q] += wd0[q] * x2 + ws0[q] * dist;
            acc1[q] += wd1[q] * x2 + ws1[q] * dist;
        }
        float h0, h1;
        { float iv = sigf(acc0[0]), fv = sigf(acc0[1]), gv = tanhf_(acc0[2]), ov = sigf(acc0[3]);
          cst0 = fv * cst0 + iv * gv; h0 = ov * tanhf_(cst0); }
        { float iv = sigf(acc1[0]), fv = sigf(acc1[1]), gv = tanhf_(acc1[2]), ov = sigf(acc1[3]);
          cst1 = fv * cst1 + iv * gv; h1 = ov * tanhf_(cst1); }
        const int j0 = (w << 2) | lg;
        hn[ln * HROW + j0] = f2b(h0);
        hn[ln * HROW + j0 + 32] = f2b(h1);
        if (writer) {
            if (is_f32) { out_f[t*3] = x0f; out_f[t*3+1] = x1f; out_f[t*3+2] = x2; }
            else { out_h[t*3] = f2b(x0f); out_h[t*3+1] = f2b(x1f); out_h[t*3+2] = f2b(x2); }
        }
        // prefetch next step's stream inputs (rides over the lgkm-only barrier)
        if (lg == 1) ldnoise(t + 1 < HISTN ? t + 1 : HISTN);
        if (lg == 0 && t == HISTN - 1) ldgd(0);
        sync_lds();
        pc ^= 1;
    }

    // ================= generation: 193 steps, TWO barriers each =================
#pragma unroll 1
    for (int tg = 0; tg < TGEN; tg++) {
        const u16* hc = hst[pc];
        u16* hn = hst[pc ^ 1];
        short8v bf0 = *(const short8v*)&hc[ln * HROW + lg * 8];
        short8v bf1 = *(const short8v*)&hc[ln * HROW + 32 + lg * 8];
        short8v bf2 = mkbf2(cv0, cv1);
        // h + stream-x contributions (dp/dist not needed yet)
        f32x4 acc0 = bias0, acc1 = bias1;
        acc0 = __builtin_amdgcn_mfma_f32_16x16x32_bf16(a00, bf0, acc0, 0, 0, 0);
        acc0 = __builtin_amdgcn_mfma_f32_16x16x32_bf16(a01, bf1, acc0, 0, 0, 0);
        acc0 = __builtin_amdgcn_mfma_f32_16x16x32_bf16(a02, bf2, acc0, 0, 0, 0);
        acc1 = __builtin_amdgcn_mfma_f32_16x16x32_bf16(a10, bf0, acc1, 0, 0, 0);
        acc1 = __builtin_amdgcn_mfma_f32_16x16x32_bf16(a11, bf1, acc1, 0, 0, 0);
        acc1 = __builtin_amdgcn_mfma_f32_16x16x32_bf16(a12, bf2, acc1, 0, 0, 0);
        if (mlpw) {   // MLP head on h_{t-1}; in-wave reduce over lg via shfl_xor
            f32x4 m0 = b1v;
            m0 = __builtin_amdgcn_mfma_f32_16x16x32_bf16(w1F0, bf0, m0, 0, 0, 0);
            m0 = __builtin_amdgcn_mfma_f32_16x16x32_bf16(w1F1, bf1, m0, 0, 0, 0);
            float p = w2L[0] * tanhf_(m0[0]) + w2L[1] * tanhf_(m0[1])
                    + w2L[2] * tanhf_(m0[2]) + w2L[3] * tanhf_(m0[3]);
            p += __shfl_xor(p, 16);
            p += __shfl_xor(p, 32);
            if (lg == 0) zpl[(ln << 2) | (w - 4)] = p;
        }
        sync_lds();   // B1: MLP partials visible
        // every lane redundantly finishes the head (replicated, bit-identical)
        float4 zr = *(const float4*)&zpl[ln << 2];
        float dp = 24.0f * tanhf_(b2v + zr.x + zr.y + zr.z + zr.w);
        dist += dp;
#pragma unroll
        for (int q = 0; q < 4; q++) {
            acc0[q] += wd0[q] * dp + ws0[q] * dist;
            acc1[q] += wd1[q] * dp + ws1[q] * dist;
        }
        float h0, h1;
        { float iv = sigf(acc0[0]), fv = sigf(acc0[1]), gv = tanhf_(acc0[2]), ov = sigf(acc0[3]);
          cst0 = fv * cst0 + iv * gv; h0 = ov * tanhf_(cst0); }
        { float iv = sigf(acc1[0]), fv = sigf(acc1[1]), gv = tanhf_(acc1[2]), ov = sigf(acc1[3]);
          cst1 = fv * cst1 + iv * gv; h1 = ov * tanhf_(cst1); }
        const int j0 = (w << 2) | lg;
        hn[ln * HROW + j0] = f2b(h0);
        hn[ln * HROW + j0 + 32] = f2b(h1);
        if (writer) {
            const int to = HISTN + tg;
            if (is_f32) { out_f[to*3] = cv0; out_f[to*3+1] = cv1; out_f[to*3+2] = dp; }
            else { out_h[to*3] = f2b(cv0); out_h[to*3+1] = f2b(cv1); out_h[to*3+2] = f2b(dp); }
        }
        if (tg + 1 < TGEN) {   // prefetch next step's gd/noise
            if (lg == 0) ldgd(tg + 1);
            if (lg == 1) {
                if (tg + 1 < TGEN - 1) ldnoise(HISTN + tg + 1);
                else { n01 = n23 = n45 = n67 = 0; }
            }
        }
        sync_lds();   // B2: h_t visible
        pc ^= 1;
    }
}

extern "C" void kernel_launch(void* const* d_in, const int* in_sizes, int n_in,
                              void* d_out, int out_size, void* d_ws, size_t ws_size,
                              hipStream_t stream) {
    (void)in_sizes; (void)n_in; (void)d_ws; (void)ws_size; (void)out_size;
    lstm_gen_kernel<<<512, 512, 0, stream>>>(
        d_in[0], d_in[1], d_in[2], d_in[3], d_in[4], d_in[5],
        d_in[6], d_in[7], d_in[8], d_in[9], d_in[10], d_out);
}